// Round 7
// baseline (159.833 us; speedup 1.0000x reference)
//
#include <hip/hip_runtime.h>
#include <math.h>
#include <stdint.h>

#define S_N 2048
#define X_N 2048
#define G_N 2
#define F_N 3072

// GEMM tile: 256(M) x 128(N), BK=64, 512 threads = 8 waves.
// 4 wave-positions of 128x64 output; 2 waves per position split the K-tile
// (kh = wave&1 takes k-chunks 0..3 / 4..7), pair-summed via LDS scratch.
#define TM 256
#define TN 128
#define BK 64
#define ITERS (F_N / BK)  // 48
#define NBUF 3            // triple buffer: no vmcnt(0) drain in main loop

typedef __bf16 bf16;
typedef __bf16 bf16x4 __attribute__((ext_vector_type(4)));
typedef __bf16 bf16x8 __attribute__((ext_vector_type(8)));
typedef float f32x4 __attribute__((ext_vector_type(4)));
typedef int i32x4 __attribute__((ext_vector_type(4)));

// async global->LDS, 16B per lane; LDS dest = wave-uniform base + lane*16
__device__ __forceinline__ void gload_lds16(const bf16* g, void* l) {
  __builtin_amdgcn_global_load_lds(
      (const __attribute__((address_space(1))) void*)g,
      (__attribute__((address_space(3))) void*)l, 16, 0, 0);
}

// ---------------- P0: prep (k_const folded in) ------------------------------
// 256 blocks x 512 thr, 16 rows/block (32 lanes per row, 24 float4 chunks).
// rinv staged in LDS once; both gradations in one pass. Each block redundantly
// computes constg (12 logf/thread, stdv L3-resident) and folds it into A:
//   A'[g,s] = ||u||^2 - 2*constg[g]  =>  logits = uv - 0.5*(A'+C) includes it.
__global__ __launch_bounds__(512) void k_prep(
    const float* __restrict__ samples, const float* __restrict__ xin,
    const float* __restrict__ stdv,
    bf16* __restrict__ U, bf16* __restrict__ V,
    float* __restrict__ A, float* __restrict__ C) {
  __shared__ float rlds[6432];  // [0,6144): rinv g0|g1; [6400,6416): log partials
  int t = threadIdx.x;
  int bid = blockIdx.x;
  int lane = t & 63, wv = t >> 6;

  for (int i = t; i < 2 * F_N; i += 512) rlds[i] = 1.0f / stdv[i];

  // constg: sum log(std) per g, reduced wave -> block
  float sl0 = 0.f, sl1 = 0.f;
  for (int i = t; i < F_N; i += 512) {
    sl0 += logf(stdv[i]);
    sl1 += logf(stdv[F_N + i]);
  }
  for (int o = 32; o; o >>= 1) { sl0 += __shfl_xor(sl0, o); sl1 += __shfl_xor(sl1, o); }
  if (lane == 0) { rlds[6400 + wv] = sl0; rlds[6408 + wv] = sl1; }
  __syncthreads();
  float t0 = 0.f, t1 = 0.f;
#pragma unroll
  for (int w2 = 0; w2 < 8; ++w2) { t0 += rlds[6400 + w2]; t1 += rlds[6408 + w2]; }
  const float KLOG = -0.5f * (float)F_N * 1.8378770664093453f;
  float c0 = KLOG - t0, c1 = KLOG - t1;

  // 16 rows per block, 32 lanes per row
  int l32 = t & 31;
  int rr = bid * 16 + (t >> 5);        // 0..4095
  bool isS = rr < S_N;
  int rx = isS ? rr : rr - S_N;
  const float* src = isS ? samples + (size_t)rx * F_N : xin + (size_t)rx * F_N;
  bf16* d0 = isS ? U + (size_t)rx * F_N : V + (size_t)rx * F_N;
  bf16* d1 = isS ? U + ((size_t)S_N + rx) * F_N : V + ((size_t)X_N + rx) * F_N;
  float a0 = 0.f, a1 = 0.f;
#pragma unroll 4
  for (int k = 0; k < 24; ++k) {
    int c4 = l32 + k * 32;
    float4 sv = ((const float4*)src)[c4];
    float4 q0 = ((const float4*)rlds)[c4];
    float4 q1 = ((const float4*)rlds)[768 + c4];
    bf16x4 b0, b1;
    b0[0] = (bf16)(sv.x * q0.x); b0[1] = (bf16)(sv.y * q0.y);
    b0[2] = (bf16)(sv.z * q0.z); b0[3] = (bf16)(sv.w * q0.w);
    b1[0] = (bf16)(sv.x * q1.x); b1[1] = (bf16)(sv.y * q1.y);
    b1[2] = (bf16)(sv.z * q1.z); b1[3] = (bf16)(sv.w * q1.w);
    float f0 = (float)b0[0], f1 = (float)b0[1], f2 = (float)b0[2], f3 = (float)b0[3];
    a0 += f0 * f0 + f1 * f1 + f2 * f2 + f3 * f3;
    float h0 = (float)b1[0], h1 = (float)b1[1], h2 = (float)b1[2], h3 = (float)b1[3];
    a1 += h0 * h0 + h1 * h1 + h2 * h2 + h3 * h3;
    ((bf16x4*)d0)[c4] = b0;
    ((bf16x4*)d1)[c4] = b1;
  }
  for (int o = 16; o; o >>= 1) { a0 += __shfl_xor(a0, o); a1 += __shfl_xor(a1, o); }
  if (l32 == 0) {
    if (isS) { A[rx] = a0 - 2.f * c0; A[S_N + rx] = a1 - 2.f * c1; }
    else     { C[rx] = a0;            C[X_N + rx] = a1; }
  }
}

// ---------------- P1: logits[g,s,x] = (u v^T)[s,x] - 0.5*(A'[g,s]+C[g,x]) ---
// R7 schedule: ONE barrier per K-tile (was 4). Sync ledger:
//  - frag reads of buf[it+1] sit after {vmcnt(6); s_barrier} => all waves'
//    tile-(it+1) DMAs landed (vmcnt asm has "memory" clobber; sched_barrier(0)
//    pins the reads below the barrier).
//  - WAR: gloads of iteration it target buf[(it+2)%3], whose last reads (frag
//    reads for tile it-1, issued in iteration it-2's tail) completed before
//    iteration it-1's MFMA consumed them (compiler lgkm guard), which precedes
//    barrier(it-1) < gloads(it). Two barriers of separation.
// Within a barrier window the 8 waves drift: one wave's MFMA burst covers
// another's ds_reads — DS pipe (~1536cy/CU) and MFMA pipe (~1242cy) drain
// concurrently instead of alternating (the R3 4-barrier ceiling).
__global__ __launch_bounds__(512, 2) void k_gemm(const bf16* __restrict__ U, const bf16* __restrict__ V,
                                                 const float* __restrict__ A, const float* __restrict__ C,
                                                 float* __restrict__ logits) {
  // [0, 6144): ldsA (3 bufs x 2048 slots); [6144, 9216): ldsB (3 x 1024). 144 KiB.
  __shared__ i32x4 lds[NBUF * 2048 + NBUF * 1024];
  i32x4* ldsA = lds;
  i32x4* ldsB = lds + NBUF * 2048;

  int t = threadIdx.x;
  int g = blockIdx.z;
  int bm = blockIdx.y * TM;
  int bn = blockIdx.x * TN;

  const bf16* Ub = U + ((size_t)g * S_N + bm) * F_N;
  const bf16* Vb = V + ((size_t)g * X_N + bn) * F_N;

  int wave = t >> 6, lane = t & 63;
  int pos = wave >> 1;                 // 0..3: output position
  int kh = wave & 1;                   // K-half of each BK=64 tile
  int wm = pos >> 1;                   // A rows: wm*128
  int wn = pos & 1;                    // B rows: wn*64
  int r = lane & 15, q = lane >> 4;
  int fr = (r >> 1) & 7;               // 3-bit read swizzle
  int ck = (kh * 4 + q) ^ fr;          // chunk-in-row for this wave's K-half
  int abase = (wm * 128 + r) * 8;
  int bbase = (wn * 64 + r) * 8;

  // Staging: slot s = t + j*512 holds global chunk (row=s>>3, (s&7)^((s>>4)&7)).
  int row0 = t >> 3;                   // 0..63
  int gcc = (t & 7) ^ ((t >> 4) & 7);
  const bf16* gA[4];
  const bf16* gB[2];
#pragma unroll
  for (int j = 0; j < 4; ++j) gA[j] = Ub + (size_t)(row0 + j * 64) * F_N + gcc * 8;
#pragma unroll
  for (int j = 0; j < 2; ++j) gB[j] = Vb + (size_t)(row0 + j * 64) * F_N + gcc * 8;

  f32x4 acc[8][4] = {};
  bf16x8 af[8], bfr[4];

  // prologue: tile0 -> buf0, tile1 -> buf1 (6 loads each); read tile0 frags
#pragma unroll
  for (int j = 0; j < 4; ++j) gload_lds16(gA[j], &ldsA[0 * 2048 + t + j * 512]);
#pragma unroll
  for (int j = 0; j < 2; ++j) gload_lds16(gB[j], &ldsB[0 * 1024 + t + j * 512]);
#pragma unroll
  for (int j = 0; j < 4; ++j) gload_lds16(gA[j] + BK, &ldsA[1 * 2048 + t + j * 512]);
#pragma unroll
  for (int j = 0; j < 2; ++j) gload_lds16(gB[j] + BK, &ldsB[1 * 1024 + t + j * 512]);
  asm volatile("s_waitcnt vmcnt(6)" ::: "memory");  // tile0 landed (per-wave)
  __builtin_amdgcn_s_barrier();                      // ...and for ALL waves
  __builtin_amdgcn_sched_barrier(0);
#pragma unroll
  for (int mi = 0; mi < 8; ++mi)
    af[mi] = __builtin_bit_cast(bf16x8, ldsA[abase + mi * 128 + ck]);
#pragma unroll
  for (int ni = 0; ni < 4; ++ni)
    bfr[ni] = __builtin_bit_cast(bf16x8, ldsB[bbase + ni * 128 + ck]);

  int cur = 0;
  for (int it = 0; it < ITERS; ++it) {
    int k2 = it + 2;
    int pk = (k2 < ITERS ? k2 : 0) * BK;  // clamped: uniform vmcnt math in tail
    int stg = (cur >= 1) ? cur - 1 : 2;   // (cur+2)%3 — tile it+2's buffer
    int nxt = (cur == 2) ? 0 : cur + 1;
    const i32x4* LAn = ldsA + nxt * 2048;
    const i32x4* LBn = ldsB + nxt * 1024;

    // issue next-next tile DMA early (hides HBM latency under MFMA burst)
    gload_lds16(gA[0] + pk, &ldsA[stg * 2048 + t]);
    gload_lds16(gA[1] + pk, &ldsA[stg * 2048 + t + 512]);
    gload_lds16(gA[2] + pk, &ldsA[stg * 2048 + t + 1024]);
    gload_lds16(gA[3] + pk, &ldsA[stg * 2048 + t + 1536]);
    gload_lds16(gB[0] + pk, &ldsB[stg * 1024 + t]);
    gload_lds16(gB[1] + pk, &ldsB[stg * 1024 + t + 512]);

    // full K-tile MFMA burst (frags pre-read last iteration; lgkm-guarded)
    __builtin_amdgcn_s_setprio(1);
#pragma unroll
    for (int mi = 0; mi < 8; ++mi)
#pragma unroll
      for (int ni = 0; ni < 4; ++ni)
        acc[mi][ni] = __builtin_amdgcn_mfma_f32_16x16x32_bf16(af[mi], bfr[ni], acc[mi][ni], 0, 0, 0);
    __builtin_amdgcn_s_setprio(0);

    // outstanding: tile it+1 (6, oldest) + tile it+2 (6) -> tile it+1 landed
    asm volatile("s_waitcnt vmcnt(6)" ::: "memory");
    __builtin_amdgcn_s_barrier();       // all waves' it+1 DMAs landed
    __builtin_amdgcn_sched_barrier(0);  // pin reads below the barrier
#pragma unroll
    for (int mi = 0; mi < 8; ++mi)
      af[mi] = __builtin_bit_cast(bf16x8, LAn[abase + mi * 128 + ck]);
#pragma unroll
    for (int ni = 0; ni < 4; ++ni)
      bfr[ni] = __builtin_bit_cast(bf16x8, LBn[bbase + ni * 128 + ck]);

    cur = nxt;
  }

  // ---- epilogue: drain tail DMA + outstanding reads before LDS scratch reuse
  asm volatile("s_waitcnt vmcnt(0) lgkmcnt(0)" ::: "memory");
  __builtin_amdgcn_s_barrier();

  // pair half-exchange: wave w and w^1 share one 128x64 output.
  // kh=0 keeps ni{0,1}, writes ni{2,3}; kh=1 keeps ni{2,3}, writes ni{0,1}.
  f32x4* scr = (f32x4*)lds;
  {
    f32x4* mw = scr + wave * 1024;
    if (kh == 0) {
#pragma unroll
      for (int mi = 0; mi < 8; ++mi)
#pragma unroll
        for (int nl = 0; nl < 2; ++nl)
          mw[(mi * 2 + nl) * 64 + lane] = acc[mi][2 + nl];
    } else {
#pragma unroll
      for (int mi = 0; mi < 8; ++mi)
#pragma unroll
        for (int nl = 0; nl < 2; ++nl)
          mw[(mi * 2 + nl) * 64 + lane] = acc[mi][nl];
    }
  }
  __syncthreads();
  {
    const f32x4* pw = scr + (wave ^ 1) * 1024;
    if (kh == 0) {
#pragma unroll
      for (int mi = 0; mi < 8; ++mi)
#pragma unroll
        for (int nl = 0; nl < 2; ++nl)
          acc[mi][nl] += pw[(mi * 2 + nl) * 64 + lane];
    } else {
#pragma unroll
      for (int mi = 0; mi < 8; ++mi)
#pragma unroll
        for (int nl = 0; nl < 2; ++nl)
          acc[mi][2 + nl] += pw[(mi * 2 + nl) * 64 + lane];
    }
  }

  // store: kh=0 -> cols [0,32), kh=1 -> cols [32,64) of the pair's 128x64 tile.
  // C/D layout: col=lane&15, row=(lane>>4)*4+reg
  const float* Ap = A + (size_t)g * S_N + bm + wm * 128;
  const float* Cp = C + (size_t)g * X_N + bn + wn * 64 + kh * 32;
  float cv[2];
  cv[0] = Cp[r]; cv[1] = Cp[16 + r];
#pragma unroll
  for (int mi = 0; mi < 8; ++mi) {
#pragma unroll
    for (int i = 0; i < 4; ++i) {
      int rowl = mi * 16 + q * 4 + i;
      float av = Ap[rowl];
      float* orow = logits + ((size_t)g * S_N + bm + wm * 128 + rowl) * X_N + bn + wn * 64 + kh * 32;
      if (kh == 0) {
        orow[r]      = acc[mi][0][i] - 0.5f * (av + cv[0]);
        orow[16 + r] = acc[mi][1][i] - 0.5f * (av + cv[1]);
      } else {
        orow[r]      = acc[mi][2][i] - 0.5f * (av + cv[0]);
        orow[16 + r] = acc[mi][3][i] - 0.5f * (av + cv[1]);
      }
    }
  }
}

// ---------------- P2: out[s] = LSE over (g,x) of logits - log(X*G) ----------
// (constg already folded into logits via A')
__global__ void k_lse(const float* __restrict__ logits, float* __restrict__ out) {
  int s = blockIdx.x, t = threadIdx.x;
  const float4* p0 = (const float4*)(logits + (size_t)s * X_N);
  const float4* p1 = (const float4*)(logits + ((size_t)S_N + s) * X_N);
  float4 v[4];
  v[0] = p0[t]; v[1] = p0[t + 256];
  v[2] = p1[t]; v[3] = p1[t + 256];

  float m = v[0].x;
#pragma unroll
  for (int j = 0; j < 4; ++j) {
    m = fmaxf(m, v[j].x); m = fmaxf(m, v[j].y);
    m = fmaxf(m, v[j].z); m = fmaxf(m, v[j].w);
  }
  for (int o = 32; o; o >>= 1) m = fmaxf(m, __shfl_xor(m, o));
  __shared__ float redm[4];
  __shared__ float reds[4];
  int w = t >> 6, l = t & 63;
  if (l == 0) redm[w] = m;
  __syncthreads();
  m = fmaxf(fmaxf(redm[0], redm[1]), fmaxf(redm[2], redm[3]));

  float sum = 0.f;
#pragma unroll
  for (int j = 0; j < 4; ++j) {
    sum += expf(v[j].x - m) + expf(v[j].y - m) + expf(v[j].z - m) + expf(v[j].w - m);
  }
  for (int o = 32; o; o >>= 1) sum += __shfl_xor(sum, o);
  if (l == 0) reds[w] = sum;
  __syncthreads();
  if (t == 0) {
    float tot = reds[0] + reds[1] + reds[2] + reds[3];
    out[s] = m + logf(tot) - 8.317766166719343f;  // log(4096)
  }
}

extern "C" void kernel_launch(void* const* d_in, const int* in_sizes, int n_in,
                              void* d_out, int out_size, void* d_ws, size_t ws_size,
                              hipStream_t stream) {
  const float* samples = (const float*)d_in[0];  // [S, F] fp32
  const float* xin     = (const float*)d_in[1];  // [X, F] fp32
  const float* stdv    = (const float*)d_in[2];  // [G, F] fp32
  float* out = (float*)d_out;                    // [S] fp32

  char* ws = (char*)d_ws;
  size_t off = 0;
  bf16* U = (bf16*)(ws + off);        off += (size_t)G_N * S_N * F_N * 2;  // 25.2 MB
  bf16* V = (bf16*)(ws + off);        off += (size_t)G_N * X_N * F_N * 2;  // 25.2 MB
  float* logits = (float*)(ws + off); off += (size_t)G_N * S_N * X_N * 4;  // 33.6 MB
  float* A = (float*)(ws + off);      off += (size_t)G_N * S_N * 4;
  float* C = (float*)(ws + off);      off += (size_t)G_N * X_N * 4;

  k_prep<<<dim3(256), dim3(512), 0, stream>>>(samples, xin, stdv, U, V, A, C);
  k_gemm<<<dim3(X_N / TN, S_N / TM, G_N), dim3(512), 0, stream>>>(U, V, A, C, logits);
  k_lse<<<dim3(S_N), dim3(256), 0, stream>>>(logits, out);
}

// Round 8
// 158.595 us; speedup vs baseline: 1.0078x; 1.0078x over previous
//
#include <hip/hip_runtime.h>
#include <math.h>
#include <stdint.h>

#define S_N 2048
#define X_N 2048
#define G_N 2
#define F_N 3072

// GEMM tile: 256(M) x 128(N), BK=64, 512 threads = 8 waves.
// 4 wave-positions of 128x64 output; 2 waves per position split the K-tile
// (kh = wave&1 takes k-chunks 0..3 / 4..7), pair-summed via LDS scratch.
#define TM 256
#define TN 128
#define BK 64
#define ITERS (F_N / BK)  // 48
#define NBUF 3            // triple buffer: no vmcnt(0) drain in main loop

typedef __bf16 bf16;
typedef __bf16 bf16x4 __attribute__((ext_vector_type(4)));
typedef __bf16 bf16x8 __attribute__((ext_vector_type(8)));
typedef float f32x4 __attribute__((ext_vector_type(4)));
typedef int i32x4 __attribute__((ext_vector_type(4)));

// async global->LDS, 16B per lane; LDS dest = wave-uniform base + lane*16
__device__ __forceinline__ void gload_lds16(const bf16* g, void* l) {
  __builtin_amdgcn_global_load_lds(
      (const __attribute__((address_space(1))) void*)g,
      (__attribute__((address_space(3))) void*)l, 16, 0, 0);
}

// ---------------- P0: prep (k_const folded in) ------------------------------
// 256 blocks x 512 thr, 16 rows/block (32 lanes per row, 24 float4 chunks).
// rinv staged in LDS once; both gradations in one pass. Each block redundantly
// computes constg (12 logf/thread, stdv L3-resident) and folds it into A:
//   A'[g,s] = ||u||^2 - 2*constg[g]  =>  logits = uv - 0.5*(A'+C) includes it.
__global__ __launch_bounds__(512) void k_prep(
    const float* __restrict__ samples, const float* __restrict__ xin,
    const float* __restrict__ stdv,
    bf16* __restrict__ U, bf16* __restrict__ V,
    float* __restrict__ A, float* __restrict__ C) {
  __shared__ float rlds[6432];  // [0,6144): rinv g0|g1; [6400,6416): log partials
  int t = threadIdx.x;
  int bid = blockIdx.x;
  int lane = t & 63, wv = t >> 6;

  for (int i = t; i < 2 * F_N; i += 512) rlds[i] = 1.0f / stdv[i];

  // constg: sum log(std) per g, reduced wave -> block
  float sl0 = 0.f, sl1 = 0.f;
  for (int i = t; i < F_N; i += 512) {
    sl0 += logf(stdv[i]);
    sl1 += logf(stdv[F_N + i]);
  }
  for (int o = 32; o; o >>= 1) { sl0 += __shfl_xor(sl0, o); sl1 += __shfl_xor(sl1, o); }
  if (lane == 0) { rlds[6400 + wv] = sl0; rlds[6408 + wv] = sl1; }
  __syncthreads();
  float t0 = 0.f, t1 = 0.f;
#pragma unroll
  for (int w2 = 0; w2 < 8; ++w2) { t0 += rlds[6400 + w2]; t1 += rlds[6408 + w2]; }
  const float KLOG = -0.5f * (float)F_N * 1.8378770664093453f;
  float c0 = KLOG - t0, c1 = KLOG - t1;

  // 16 rows per block, 32 lanes per row
  int l32 = t & 31;
  int rr = bid * 16 + (t >> 5);        // 0..4095
  bool isS = rr < S_N;
  int rx = isS ? rr : rr - S_N;
  const float* src = isS ? samples + (size_t)rx * F_N : xin + (size_t)rx * F_N;
  bf16* d0 = isS ? U + (size_t)rx * F_N : V + (size_t)rx * F_N;
  bf16* d1 = isS ? U + ((size_t)S_N + rx) * F_N : V + ((size_t)X_N + rx) * F_N;
  float a0 = 0.f, a1 = 0.f;
#pragma unroll 4
  for (int k = 0; k < 24; ++k) {
    int c4 = l32 + k * 32;
    float4 sv = ((const float4*)src)[c4];
    float4 q0 = ((const float4*)rlds)[c4];
    float4 q1 = ((const float4*)rlds)[768 + c4];
    bf16x4 b0, b1;
    b0[0] = (bf16)(sv.x * q0.x); b0[1] = (bf16)(sv.y * q0.y);
    b0[2] = (bf16)(sv.z * q0.z); b0[3] = (bf16)(sv.w * q0.w);
    b1[0] = (bf16)(sv.x * q1.x); b1[1] = (bf16)(sv.y * q1.y);
    b1[2] = (bf16)(sv.z * q1.z); b1[3] = (bf16)(sv.w * q1.w);
    float f0 = (float)b0[0], f1 = (float)b0[1], f2 = (float)b0[2], f3 = (float)b0[3];
    a0 += f0 * f0 + f1 * f1 + f2 * f2 + f3 * f3;
    float h0 = (float)b1[0], h1 = (float)b1[1], h2 = (float)b1[2], h3 = (float)b1[3];
    a1 += h0 * h0 + h1 * h1 + h2 * h2 + h3 * h3;
    ((bf16x4*)d0)[c4] = b0;
    ((bf16x4*)d1)[c4] = b1;
  }
  for (int o = 16; o; o >>= 1) { a0 += __shfl_xor(a0, o); a1 += __shfl_xor(a1, o); }
  if (l32 == 0) {
    if (isS) { A[rx] = a0 - 2.f * c0; A[S_N + rx] = a1 - 2.f * c1; }
    else     { C[rx] = a0;            C[X_N + rx] = a1; }
  }
}

// ---------------- P1: logits[g,s,x] = (u v^T)[s,x] - 0.5*(A'[g,s]+C[g,x]) ---
// R8 = R7 single-barrier schedule + consumption-ordered reads/MFMAs.
// Reads issue bfr[0..3] then af[0..7]; MFMA nest is ni OUTER / mi INNER, so
// MFMA k needs only read 5+k-1 (counted lgkmcnt(7..0)), and the ni=1..3 block
// (24/32 MFMAs) runs with zero lgkm waits — DS drain rides UNDER the MFMA
// stream instead of preceding it (R7's mi-outer order forced a full drain by
// MFMA #4: bfr[0..3] were the LAST reads issued).
// Sync ledger unchanged from R7 (one vmcnt(6)+barrier per K-tile; NBUF=3
// gives >=2 barriers of WAR separation for the DMA target buffer).
__global__ __launch_bounds__(512, 2) void k_gemm(const bf16* __restrict__ U, const bf16* __restrict__ V,
                                                 const float* __restrict__ A, const float* __restrict__ C,
                                                 float* __restrict__ logits) {
  // [0, 6144): ldsA (3 bufs x 2048 slots); [6144, 9216): ldsB (3 x 1024). 144 KiB.
  __shared__ i32x4 lds[NBUF * 2048 + NBUF * 1024];
  i32x4* ldsA = lds;
  i32x4* ldsB = lds + NBUF * 2048;

  int t = threadIdx.x;
  int g = blockIdx.z;
  int bm = blockIdx.y * TM;
  int bn = blockIdx.x * TN;

  const bf16* Ub = U + ((size_t)g * S_N + bm) * F_N;
  const bf16* Vb = V + ((size_t)g * X_N + bn) * F_N;

  int wave = t >> 6, lane = t & 63;
  int pos = wave >> 1;                 // 0..3: output position
  int kh = wave & 1;                   // K-half of each BK=64 tile
  int wm = pos >> 1;                   // A rows: wm*128
  int wn = pos & 1;                    // B rows: wn*64
  int r = lane & 15, q = lane >> 4;
  int fr = (r >> 1) & 7;               // 3-bit read swizzle
  int ck = (kh * 4 + q) ^ fr;          // chunk-in-row for this wave's K-half
  int abase = (wm * 128 + r) * 8;
  int bbase = (wn * 64 + r) * 8;

  // Staging: slot s = t + j*512 holds global chunk (row=s>>3, (s&7)^((s>>4)&7)).
  int row0 = t >> 3;                   // 0..63
  int gcc = (t & 7) ^ ((t >> 4) & 7);
  const bf16* gA[4];
  const bf16* gB[2];
#pragma unroll
  for (int j = 0; j < 4; ++j) gA[j] = Ub + (size_t)(row0 + j * 64) * F_N + gcc * 8;
#pragma unroll
  for (int j = 0; j < 2; ++j) gB[j] = Vb + (size_t)(row0 + j * 64) * F_N + gcc * 8;

  f32x4 acc[8][4] = {};
  bf16x8 af[8], bfr[4];

  // prologue: tile0 -> buf0, tile1 -> buf1 (6 loads each); read tile0 frags
#pragma unroll
  for (int j = 0; j < 4; ++j) gload_lds16(gA[j], &ldsA[0 * 2048 + t + j * 512]);
#pragma unroll
  for (int j = 0; j < 2; ++j) gload_lds16(gB[j], &ldsB[0 * 1024 + t + j * 512]);
#pragma unroll
  for (int j = 0; j < 4; ++j) gload_lds16(gA[j] + BK, &ldsA[1 * 2048 + t + j * 512]);
#pragma unroll
  for (int j = 0; j < 2; ++j) gload_lds16(gB[j] + BK, &ldsB[1 * 1024 + t + j * 512]);
  asm volatile("s_waitcnt vmcnt(6)" ::: "memory");  // tile0 landed (per-wave)
  __builtin_amdgcn_s_barrier();                      // ...and for ALL waves
  __builtin_amdgcn_sched_barrier(0);
#pragma unroll
  for (int ni = 0; ni < 4; ++ni)
    bfr[ni] = __builtin_bit_cast(bf16x8, ldsB[bbase + ni * 128 + ck]);
#pragma unroll
  for (int mi = 0; mi < 8; ++mi)
    af[mi] = __builtin_bit_cast(bf16x8, ldsA[abase + mi * 128 + ck]);

  int cur = 0;
  for (int it = 0; it < ITERS; ++it) {
    int k2 = it + 2;
    int pk = (k2 < ITERS ? k2 : 0) * BK;  // clamped: uniform vmcnt math in tail
    int stg = (cur >= 1) ? cur - 1 : 2;   // (cur+2)%3 — tile it+2's buffer
    int nxt = (cur == 2) ? 0 : cur + 1;
    const i32x4* LAn = ldsA + nxt * 2048;
    const i32x4* LBn = ldsB + nxt * 1024;

    // issue next-next tile DMA early (hides HBM latency under MFMA burst)
    gload_lds16(gA[0] + pk, &ldsA[stg * 2048 + t]);
    gload_lds16(gA[1] + pk, &ldsA[stg * 2048 + t + 512]);
    gload_lds16(gA[2] + pk, &ldsA[stg * 2048 + t + 1024]);
    gload_lds16(gA[3] + pk, &ldsA[stg * 2048 + t + 1536]);
    gload_lds16(gB[0] + pk, &ldsB[stg * 1024 + t]);
    gload_lds16(gB[1] + pk, &ldsB[stg * 1024 + t + 512]);

    // full K-tile MFMA burst. ni OUTER / mi INNER: first MFMA gated on read 5,
    // each mi adds one read; ni=1..3 reuse registers wait-free.
    __builtin_amdgcn_s_setprio(1);
#pragma unroll
    for (int ni = 0; ni < 4; ++ni)
#pragma unroll
      for (int mi = 0; mi < 8; ++mi)
        acc[mi][ni] = __builtin_amdgcn_mfma_f32_16x16x32_bf16(af[mi], bfr[ni], acc[mi][ni], 0, 0, 0);
    __builtin_amdgcn_s_setprio(0);

    // outstanding: tile it+1 (6, oldest) + tile it+2 (6) -> tile it+1 landed
    asm volatile("s_waitcnt vmcnt(6)" ::: "memory");
    __builtin_amdgcn_s_barrier();       // all waves' it+1 DMAs landed
    __builtin_amdgcn_sched_barrier(0);  // pin reads below the barrier
    // consumption order: bfr first, then af
#pragma unroll
    for (int ni = 0; ni < 4; ++ni)
      bfr[ni] = __builtin_bit_cast(bf16x8, LBn[bbase + ni * 128 + ck]);
#pragma unroll
    for (int mi = 0; mi < 8; ++mi)
      af[mi] = __builtin_bit_cast(bf16x8, LAn[abase + mi * 128 + ck]);

    cur = nxt;
  }

  // ---- epilogue: drain tail DMA + outstanding reads before LDS scratch reuse
  asm volatile("s_waitcnt vmcnt(0) lgkmcnt(0)" ::: "memory");
  __builtin_amdgcn_s_barrier();

  // pair half-exchange: wave w and w^1 share one 128x64 output.
  // kh=0 keeps ni{0,1}, writes ni{2,3}; kh=1 keeps ni{2,3}, writes ni{0,1}.
  f32x4* scr = (f32x4*)lds;
  {
    f32x4* mw = scr + wave * 1024;
    if (kh == 0) {
#pragma unroll
      for (int mi = 0; mi < 8; ++mi)
#pragma unroll
        for (int nl = 0; nl < 2; ++nl)
          mw[(mi * 2 + nl) * 64 + lane] = acc[mi][2 + nl];
    } else {
#pragma unroll
      for (int mi = 0; mi < 8; ++mi)
#pragma unroll
        for (int nl = 0; nl < 2; ++nl)
          mw[(mi * 2 + nl) * 64 + lane] = acc[mi][nl];
    }
  }
  __syncthreads();
  {
    const f32x4* pw = scr + (wave ^ 1) * 1024;
    if (kh == 0) {
#pragma unroll
      for (int mi = 0; mi < 8; ++mi)
#pragma unroll
        for (int nl = 0; nl < 2; ++nl)
          acc[mi][nl] += pw[(mi * 2 + nl) * 64 + lane];
    } else {
#pragma unroll
      for (int mi = 0; mi < 8; ++mi)
#pragma unroll
        for (int nl = 0; nl < 2; ++nl)
          acc[mi][2 + nl] += pw[(mi * 2 + nl) * 64 + lane];
    }
  }

  // store: kh=0 -> cols [0,32), kh=1 -> cols [32,64) of the pair's 128x64 tile.
  // C/D layout: col=lane&15, row=(lane>>4)*4+reg
  const float* Ap = A + (size_t)g * S_N + bm + wm * 128;
  const float* Cp = C + (size_t)g * X_N + bn + wn * 64 + kh * 32;
  float cv[2];
  cv[0] = Cp[r]; cv[1] = Cp[16 + r];
#pragma unroll
  for (int mi = 0; mi < 8; ++mi) {
#pragma unroll
    for (int i = 0; i < 4; ++i) {
      int rowl = mi * 16 + q * 4 + i;
      float av = Ap[rowl];
      float* orow = logits + ((size_t)g * S_N + bm + wm * 128 + rowl) * X_N + bn + wn * 64 + kh * 32;
      if (kh == 0) {
        orow[r]      = acc[mi][0][i] - 0.5f * (av + cv[0]);
        orow[16 + r] = acc[mi][1][i] - 0.5f * (av + cv[1]);
      } else {
        orow[r]      = acc[mi][2][i] - 0.5f * (av + cv[0]);
        orow[16 + r] = acc[mi][3][i] - 0.5f * (av + cv[1]);
      }
    }
  }
}

// ---------------- P2: out[s] = LSE over (g,x) of logits - log(X*G) ----------
// (constg already folded into logits via A')
__global__ void k_lse(const float* __restrict__ logits, float* __restrict__ out) {
  int s = blockIdx.x, t = threadIdx.x;
  const float4* p0 = (const float4*)(logits + (size_t)s * X_N);
  const float4* p1 = (const float4*)(logits + ((size_t)S_N + s) * X_N);
  float4 v[4];
  v[0] = p0[t]; v[1] = p0[t + 256];
  v[2] = p1[t]; v[3] = p1[t + 256];

  float m = v[0].x;
#pragma unroll
  for (int j = 0; j < 4; ++j) {
    m = fmaxf(m, v[j].x); m = fmaxf(m, v[j].y);
    m = fmaxf(m, v[j].z); m = fmaxf(m, v[j].w);
  }
  for (int o = 32; o; o >>= 1) m = fmaxf(m, __shfl_xor(m, o));
  __shared__ float redm[4];
  __shared__ float reds[4];
  int w = t >> 6, l = t & 63;
  if (l == 0) redm[w] = m;
  __syncthreads();
  m = fmaxf(fmaxf(redm[0], redm[1]), fmaxf(redm[2], redm[3]));

  float sum = 0.f;
#pragma unroll
  for (int j = 0; j < 4; ++j) {
    sum += expf(v[j].x - m) + expf(v[j].y - m) + expf(v[j].z - m) + expf(v[j].w - m);
  }
  for (int o = 32; o; o >>= 1) sum += __shfl_xor(sum, o);
  if (l == 0) reds[w] = sum;
  __syncthreads();
  if (t == 0) {
    float tot = reds[0] + reds[1] + reds[2] + reds[3];
    out[s] = m + logf(tot) - 8.317766166719343f;  // log(4096)
  }
}

extern "C" void kernel_launch(void* const* d_in, const int* in_sizes, int n_in,
                              void* d_out, int out_size, void* d_ws, size_t ws_size,
                              hipStream_t stream) {
  const float* samples = (const float*)d_in[0];  // [S, F] fp32
  const float* xin     = (const float*)d_in[1];  // [X, F] fp32
  const float* stdv    = (const float*)d_in[2];  // [G, F] fp32
  float* out = (float*)d_out;                    // [S] fp32

  char* ws = (char*)d_ws;
  size_t off = 0;
  bf16* U = (bf16*)(ws + off);        off += (size_t)G_N * S_N * F_N * 2;  // 25.2 MB
  bf16* V = (bf16*)(ws + off);        off += (size_t)G_N * X_N * F_N * 2;  // 25.2 MB
  float* logits = (float*)(ws + off); off += (size_t)G_N * S_N * X_N * 4;  // 33.6 MB
  float* A = (float*)(ws + off);      off += (size_t)G_N * S_N * 4;
  float* C = (float*)(ws + off);      off += (size_t)G_N * X_N * 4;

  k_prep<<<dim3(256), dim3(512), 0, stream>>>(samples, xin, stdv, U, V, A, C);
  k_gemm<<<dim3(X_N / TN, S_N / TM, G_N), dim3(512), 0, stream>>>(U, V, A, C, logits);
  k_lse<<<dim3(S_N), dim3(256), 0, stream>>>(logits, out);
}

// Round 9
// 155.267 us; speedup vs baseline: 1.0294x; 1.0214x over previous
//
#include <hip/hip_runtime.h>
#include <math.h>
#include <stdint.h>

#define S_N 2048
#define X_N 2048
#define G_N 2
#define F_N 3072

// GEMM tile: 256(M) x 128(N), BK=64, 512 threads = 8 waves.
// 4 wave-positions of 128x64 output; 2 waves per position split the K-tile
// (kh = wave&1 takes k-chunks 0..3 / 4..7), pair-summed via LDS scratch.
#define TM 256
#define TN 128
#define BK 64
#define ITERS (F_N / BK)  // 48
#define NBUF 3            // triple buffer: no vmcnt(0) drain in main loop

typedef __bf16 bf16;
typedef __bf16 bf16x4 __attribute__((ext_vector_type(4)));
typedef __bf16 bf16x8 __attribute__((ext_vector_type(8)));
typedef float f32x4 __attribute__((ext_vector_type(4)));
typedef int i32x4 __attribute__((ext_vector_type(4)));

// async global->LDS, 16B per lane; LDS dest = wave-uniform base + lane*16
__device__ __forceinline__ void gload_lds16(const bf16* g, void* l) {
  __builtin_amdgcn_global_load_lds(
      (const __attribute__((address_space(1))) void*)g,
      (__attribute__((address_space(3))) void*)l, 16, 0, 0);
}

// ---------------- P0: prep (k_const folded in) ------------------------------
// 256 blocks x 512 thr, 16 rows/block (32 lanes per row, 24 float4 chunks).
// rinv staged in LDS once; both gradations in one pass. Each block redundantly
// computes constg (12 logf/thread, stdv L3-resident) and folds it into A:
//   A'[g,s] = ||u||^2 - 2*constg[g]  =>  logits = uv - 0.5*(A'+C) includes it.
__global__ __launch_bounds__(512) void k_prep(
    const float* __restrict__ samples, const float* __restrict__ xin,
    const float* __restrict__ stdv,
    bf16* __restrict__ U, bf16* __restrict__ V,
    float* __restrict__ A, float* __restrict__ C) {
  __shared__ float rlds[6432];  // [0,6144): rinv g0|g1; [6400,6416): log partials
  int t = threadIdx.x;
  int bid = blockIdx.x;
  int lane = t & 63, wv = t >> 6;

  for (int i = t; i < 2 * F_N; i += 512) rlds[i] = 1.0f / stdv[i];

  // constg: sum log(std) per g, reduced wave -> block
  float sl0 = 0.f, sl1 = 0.f;
  for (int i = t; i < F_N; i += 512) {
    sl0 += logf(stdv[i]);
    sl1 += logf(stdv[F_N + i]);
  }
  for (int o = 32; o; o >>= 1) { sl0 += __shfl_xor(sl0, o); sl1 += __shfl_xor(sl1, o); }
  if (lane == 0) { rlds[6400 + wv] = sl0; rlds[6408 + wv] = sl1; }
  __syncthreads();
  float t0 = 0.f, t1 = 0.f;
#pragma unroll
  for (int w2 = 0; w2 < 8; ++w2) { t0 += rlds[6400 + w2]; t1 += rlds[6408 + w2]; }
  const float KLOG = -0.5f * (float)F_N * 1.8378770664093453f;
  float c0 = KLOG - t0, c1 = KLOG - t1;

  // 16 rows per block, 32 lanes per row
  int l32 = t & 31;
  int rr = bid * 16 + (t >> 5);        // 0..4095
  bool isS = rr < S_N;
  int rx = isS ? rr : rr - S_N;
  const float* src = isS ? samples + (size_t)rx * F_N : xin + (size_t)rx * F_N;
  bf16* d0 = isS ? U + (size_t)rx * F_N : V + (size_t)rx * F_N;
  bf16* d1 = isS ? U + ((size_t)S_N + rx) * F_N : V + ((size_t)X_N + rx) * F_N;
  float a0 = 0.f, a1 = 0.f;
#pragma unroll 4
  for (int k = 0; k < 24; ++k) {
    int c4 = l32 + k * 32;
    float4 sv = ((const float4*)src)[c4];
    float4 q0 = ((const float4*)rlds)[c4];
    float4 q1 = ((const float4*)rlds)[768 + c4];
    bf16x4 b0, b1;
    b0[0] = (bf16)(sv.x * q0.x); b0[1] = (bf16)(sv.y * q0.y);
    b0[2] = (bf16)(sv.z * q0.z); b0[3] = (bf16)(sv.w * q0.w);
    b1[0] = (bf16)(sv.x * q1.x); b1[1] = (bf16)(sv.y * q1.y);
    b1[2] = (bf16)(sv.z * q1.z); b1[3] = (bf16)(sv.w * q1.w);
    float f0 = (float)b0[0], f1 = (float)b0[1], f2 = (float)b0[2], f3 = (float)b0[3];
    a0 += f0 * f0 + f1 * f1 + f2 * f2 + f3 * f3;
    float h0 = (float)b1[0], h1 = (float)b1[1], h2 = (float)b1[2], h3 = (float)b1[3];
    a1 += h0 * h0 + h1 * h1 + h2 * h2 + h3 * h3;
    ((bf16x4*)d0)[c4] = b0;
    ((bf16x4*)d1)[c4] = b1;
  }
  for (int o = 16; o; o >>= 1) { a0 += __shfl_xor(a0, o); a1 += __shfl_xor(a1, o); }
  if (l32 == 0) {
    if (isS) { A[rx] = a0 - 2.f * c0; A[S_N + rx] = a1 - 2.f * c1; }
    else     { C[rx] = a0;            C[X_N + rx] = a1; }
  }
}

// ---------------- P1: logits[g,s,x] = (u v^T)[s,x] - 0.5*(A'[g,s]+C[g,x]) ---
// R9 = R8 core (verified, 54.2us) + XCD-aware block remap (T1).
// 1-D grid of 256; consecutive bids round-robin across the 8 XCDs, so XCD
// x = bid&7 owns the 32 blocks {bid : bid&7==x} — mapped here to 2 full
// output rows (of the 16 rows = (g,by)) x all 16 cols. Per-XCD working set:
// 2 A-panels (3 MB, fits 4 MB L2) + instantaneous B K-slices (~320 KB).
// L2-miss traffic drops ~576 MB -> ~120 MB per dispatch; A/B panel reads
// become L2 hits instead of L3/HBM refetches. GEMM math byte-identical.
__global__ __launch_bounds__(512, 2) void k_gemm(const bf16* __restrict__ U, const bf16* __restrict__ V,
                                                 const float* __restrict__ A, const float* __restrict__ C,
                                                 float* __restrict__ logits) {
  // [0, 6144): ldsA (3 bufs x 2048 slots); [6144, 9216): ldsB (3 x 1024). 144 KiB.
  __shared__ i32x4 lds[NBUF * 2048 + NBUF * 1024];
  i32x4* ldsA = lds;
  i32x4* ldsB = lds + NBUF * 2048;

  int t = threadIdx.x;

  // XCD swizzle: xcd = bid&7 (dispatch round-robin), 32 blocks per XCD.
  // Each XCD: rows {2*xcd, 2*xcd+1} of the 16 (g,by) rows, cols 0..15.
  int bid = blockIdx.x;
  int xcd = bid & 7, wi = bid >> 3;    // 8 XCDs x 32 blocks
  int rp = wi & 1, cc2 = wi >> 1;      // row-in-pair, col 0..15
  int row16 = xcd * 2 + rp;            // 0..15 = g*8 + by
  int g = row16 >> 3;
  int bm = (row16 & 7) * TM;
  int bn = cc2 * TN;

  const bf16* Ub = U + ((size_t)g * S_N + bm) * F_N;
  const bf16* Vb = V + ((size_t)g * X_N + bn) * F_N;

  int wave = t >> 6, lane = t & 63;
  int pos = wave >> 1;                 // 0..3: output position
  int kh = wave & 1;                   // K-half of each BK=64 tile
  int wm = pos >> 1;                   // A rows: wm*128
  int wn = pos & 1;                    // B rows: wn*64
  int r = lane & 15, q = lane >> 4;
  int fr = (r >> 1) & 7;               // 3-bit read swizzle
  int ck = (kh * 4 + q) ^ fr;          // chunk-in-row for this wave's K-half
  int abase = (wm * 128 + r) * 8;
  int bbase = (wn * 64 + r) * 8;

  // Staging: slot s = t + j*512 holds global chunk (row=s>>3, (s&7)^((s>>4)&7)).
  int row0 = t >> 3;                   // 0..63
  int gcc = (t & 7) ^ ((t >> 4) & 7);
  const bf16* gA[4];
  const bf16* gB[2];
#pragma unroll
  for (int j = 0; j < 4; ++j) gA[j] = Ub + (size_t)(row0 + j * 64) * F_N + gcc * 8;
#pragma unroll
  for (int j = 0; j < 2; ++j) gB[j] = Vb + (size_t)(row0 + j * 64) * F_N + gcc * 8;

  f32x4 acc[8][4] = {};
  bf16x8 af[8], bfr[4];

  // prologue: tile0 -> buf0, tile1 -> buf1 (6 loads each); read tile0 frags
#pragma unroll
  for (int j = 0; j < 4; ++j) gload_lds16(gA[j], &ldsA[0 * 2048 + t + j * 512]);
#pragma unroll
  for (int j = 0; j < 2; ++j) gload_lds16(gB[j], &ldsB[0 * 1024 + t + j * 512]);
#pragma unroll
  for (int j = 0; j < 4; ++j) gload_lds16(gA[j] + BK, &ldsA[1 * 2048 + t + j * 512]);
#pragma unroll
  for (int j = 0; j < 2; ++j) gload_lds16(gB[j] + BK, &ldsB[1 * 1024 + t + j * 512]);
  asm volatile("s_waitcnt vmcnt(6)" ::: "memory");  // tile0 landed (per-wave)
  __builtin_amdgcn_s_barrier();                      // ...and for ALL waves
  __builtin_amdgcn_sched_barrier(0);
#pragma unroll
  for (int ni = 0; ni < 4; ++ni)
    bfr[ni] = __builtin_bit_cast(bf16x8, ldsB[bbase + ni * 128 + ck]);
#pragma unroll
  for (int mi = 0; mi < 8; ++mi)
    af[mi] = __builtin_bit_cast(bf16x8, ldsA[abase + mi * 128 + ck]);

  int cur = 0;
  for (int it = 0; it < ITERS; ++it) {
    int k2 = it + 2;
    int pk = (k2 < ITERS ? k2 : 0) * BK;  // clamped: uniform vmcnt math in tail
    int stg = (cur >= 1) ? cur - 1 : 2;   // (cur+2)%3 — tile it+2's buffer
    int nxt = (cur == 2) ? 0 : cur + 1;
    const i32x4* LAn = ldsA + nxt * 2048;
    const i32x4* LBn = ldsB + nxt * 1024;

    // issue next-next tile DMA early (hides HBM latency under MFMA burst)
    gload_lds16(gA[0] + pk, &ldsA[stg * 2048 + t]);
    gload_lds16(gA[1] + pk, &ldsA[stg * 2048 + t + 512]);
    gload_lds16(gA[2] + pk, &ldsA[stg * 2048 + t + 1024]);
    gload_lds16(gA[3] + pk, &ldsA[stg * 2048 + t + 1536]);
    gload_lds16(gB[0] + pk, &ldsB[stg * 1024 + t]);
    gload_lds16(gB[1] + pk, &ldsB[stg * 1024 + t + 512]);

    // full K-tile MFMA burst. ni OUTER / mi INNER: first MFMA gated on read 5,
    // each mi adds one read; ni=1..3 reuse registers wait-free.
    __builtin_amdgcn_s_setprio(1);
#pragma unroll
    for (int ni = 0; ni < 4; ++ni)
#pragma unroll
      for (int mi = 0; mi < 8; ++mi)
        acc[mi][ni] = __builtin_amdgcn_mfma_f32_16x16x32_bf16(af[mi], bfr[ni], acc[mi][ni], 0, 0, 0);
    __builtin_amdgcn_s_setprio(0);

    // outstanding: tile it+1 (6, oldest) + tile it+2 (6) -> tile it+1 landed
    asm volatile("s_waitcnt vmcnt(6)" ::: "memory");
    __builtin_amdgcn_s_barrier();       // all waves' it+1 DMAs landed
    __builtin_amdgcn_sched_barrier(0);  // pin reads below the barrier
    // consumption order: bfr first, then af
#pragma unroll
    for (int ni = 0; ni < 4; ++ni)
      bfr[ni] = __builtin_bit_cast(bf16x8, LBn[bbase + ni * 128 + ck]);
#pragma unroll
    for (int mi = 0; mi < 8; ++mi)
      af[mi] = __builtin_bit_cast(bf16x8, LAn[abase + mi * 128 + ck]);

    cur = nxt;
  }

  // ---- epilogue: drain tail DMA + outstanding reads before LDS scratch reuse
  asm volatile("s_waitcnt vmcnt(0) lgkmcnt(0)" ::: "memory");
  __builtin_amdgcn_s_barrier();

  // pair half-exchange: wave w and w^1 share one 128x64 output.
  // kh=0 keeps ni{0,1}, writes ni{2,3}; kh=1 keeps ni{2,3}, writes ni{0,1}.
  f32x4* scr = (f32x4*)lds;
  {
    f32x4* mw = scr + wave * 1024;
    if (kh == 0) {
#pragma unroll
      for (int mi = 0; mi < 8; ++mi)
#pragma unroll
        for (int nl = 0; nl < 2; ++nl)
          mw[(mi * 2 + nl) * 64 + lane] = acc[mi][2 + nl];
    } else {
#pragma unroll
      for (int mi = 0; mi < 8; ++mi)
#pragma unroll
        for (int nl = 0; nl < 2; ++nl)
          mw[(mi * 2 + nl) * 64 + lane] = acc[mi][nl];
    }
  }
  __syncthreads();
  {
    const f32x4* pw = scr + (wave ^ 1) * 1024;
    if (kh == 0) {
#pragma unroll
      for (int mi = 0; mi < 8; ++mi)
#pragma unroll
        for (int nl = 0; nl < 2; ++nl)
          acc[mi][nl] += pw[(mi * 2 + nl) * 64 + lane];
    } else {
#pragma unroll
      for (int mi = 0; mi < 8; ++mi)
#pragma unroll
        for (int nl = 0; nl < 2; ++nl)
          acc[mi][2 + nl] += pw[(mi * 2 + nl) * 64 + lane];
    }
  }

  // store: kh=0 -> cols [0,32), kh=1 -> cols [32,64) of the pair's 128x64 tile.
  // C/D layout: col=lane&15, row=(lane>>4)*4+reg
  const float* Ap = A + (size_t)g * S_N + bm + wm * 128;
  const float* Cp = C + (size_t)g * X_N + bn + wn * 64 + kh * 32;
  float cv[2];
  cv[0] = Cp[r]; cv[1] = Cp[16 + r];
#pragma unroll
  for (int mi = 0; mi < 8; ++mi) {
#pragma unroll
    for (int i = 0; i < 4; ++i) {
      int rowl = mi * 16 + q * 4 + i;
      float av = Ap[rowl];
      float* orow = logits + ((size_t)g * S_N + bm + wm * 128 + rowl) * X_N + bn + wn * 64 + kh * 32;
      if (kh == 0) {
        orow[r]      = acc[mi][0][i] - 0.5f * (av + cv[0]);
        orow[16 + r] = acc[mi][1][i] - 0.5f * (av + cv[1]);
      } else {
        orow[r]      = acc[mi][2][i] - 0.5f * (av + cv[0]);
        orow[16 + r] = acc[mi][3][i] - 0.5f * (av + cv[1]);
      }
    }
  }
}

// ---------------- P2: out[s] = LSE over (g,x) of logits - log(X*G) ----------
// (constg already folded into logits via A')
__global__ void k_lse(const float* __restrict__ logits, float* __restrict__ out) {
  int s = blockIdx.x, t = threadIdx.x;
  const float4* p0 = (const float4*)(logits + (size_t)s * X_N);
  const float4* p1 = (const float4*)(logits + ((size_t)S_N + s) * X_N);
  float4 v[4];
  v[0] = p0[t]; v[1] = p0[t + 256];
  v[2] = p1[t]; v[3] = p1[t + 256];

  float m = v[0].x;
#pragma unroll
  for (int j = 0; j < 4; ++j) {
    m = fmaxf(m, v[j].x); m = fmaxf(m, v[j].y);
    m = fmaxf(m, v[j].z); m = fmaxf(m, v[j].w);
  }
  for (int o = 32; o; o >>= 1) m = fmaxf(m, __shfl_xor(m, o));
  __shared__ float redm[4];
  __shared__ float reds[4];
  int w = t >> 6, l = t & 63;
  if (l == 0) redm[w] = m;
  __syncthreads();
  m = fmaxf(fmaxf(redm[0], redm[1]), fmaxf(redm[2], redm[3]));

  float sum = 0.f;
#pragma unroll
  for (int j = 0; j < 4; ++j) {
    sum += expf(v[j].x - m) + expf(v[j].y - m) + expf(v[j].z - m) + expf(v[j].w - m);
  }
  for (int o = 32; o; o >>= 1) sum += __shfl_xor(sum, o);
  if (l == 0) reds[w] = sum;
  __syncthreads();
  if (t == 0) {
    float tot = reds[0] + reds[1] + reds[2] + reds[3];
    out[s] = m + logf(tot) - 8.317766166719343f;  // log(4096)
  }
}

extern "C" void kernel_launch(void* const* d_in, const int* in_sizes, int n_in,
                              void* d_out, int out_size, void* d_ws, size_t ws_size,
                              hipStream_t stream) {
  const float* samples = (const float*)d_in[0];  // [S, F] fp32
  const float* xin     = (const float*)d_in[1];  // [X, F] fp32
  const float* stdv    = (const float*)d_in[2];  // [G, F] fp32
  float* out = (float*)d_out;                    // [S] fp32

  char* ws = (char*)d_ws;
  size_t off = 0;
  bf16* U = (bf16*)(ws + off);        off += (size_t)G_N * S_N * F_N * 2;  // 25.2 MB
  bf16* V = (bf16*)(ws + off);        off += (size_t)G_N * X_N * F_N * 2;  // 25.2 MB
  float* logits = (float*)(ws + off); off += (size_t)G_N * S_N * X_N * 4;  // 33.6 MB
  float* A = (float*)(ws + off);      off += (size_t)G_N * S_N * 4;
  float* C = (float*)(ws + off);      off += (size_t)G_N * X_N * 4;

  k_prep<<<dim3(256), dim3(512), 0, stream>>>(samples, xin, stdv, U, V, A, C);
  k_gemm<<<dim3(256), dim3(512), 0, stream>>>(U, V, A, C, logits);
  k_lse<<<dim3(S_N), dim3(256), 0, stream>>>(logits, out);
}